// Round 9
// baseline (29475.272 us; speedup 1.0000x reference)
//
#include <hip/hip_runtime.h>
#include <math.h>

#define NDIM 4096
#define NR   4095        // rounds = N-1 (rotating positions)
#define NPAIRS 2048      // N/2 tables
#define CB   4           // columns per workgroup slice (r9: back to 4 for 1024 blocks)
#define NTHREADS 256
#define NWAVES (NTHREADS / 64)   // 4
#define TPT  8           // tables per thread (NPAIRS / NTHREADS)

// Precompute (c, s) per (round, table); bake in the orientation sign:
// table k at round r holds players a=(r+k)%NR (top) and b=(r-k)%NR (bottom,
// or 4095 fixed for k=0). Reference rotates (i,j)=(min,max) with
// U[i]=c*Ui-s*Uj, U[j]=s*Ui+c*Uj. If top==j negate s. top>bottom iff 0<k<=r<NR-k.
__global__ void cs_precompute(const float* __restrict__ thetas,
                              const int* __restrict__ round_theta,
                              float2* __restrict__ cs, int total) {
    int idx = blockIdx.x * blockDim.x + threadIdx.x;
    if (idx >= total) return;
    int r = idx / NPAIRS;
    int k = idx - r * NPAIRS;
    float th = thetas[round_theta[idx]];
    float s, c;
    sincosf(th, &s, &c);
    if (k > 0 && k <= r && r < NR - k) s = -s;
    cs[idx] = make_float2(c, s);
}

// Register-systolic circle method, phase-rotated in-place update, TPT=8.
// At phase p (= round mod 8): logical top[u] lives in T[(u+p)&7],
// logical bot[u] in B[(u-p)&7]. The per-round ring shift (top[u-1]<-na[u],
// bot[u+1]<-nb[u]) is a pure RENAME for u=1..6; boundary traffic (na of
// first table, nb of last) via shfl +/-1 lane and a tiny LDS ping-pong.
//
// PIN HISTORY (hard-won; the pins serve THREE functions):
//   (1) keep T/B scalarized in SSA (r7: NO pins -> SROA gave up, arrays
//       went to SCRATCH: 136GB spill traffic, 31ms. Pins are mandatory.)
//   (2) keep T/B out of AGPRs
//   (3) asm volatile = schedule fence containing prefetch hoist (r4:
//       hoisted pins -> 32 in-flight dwordx4 across phases -> spill)
// r8 proved INPUT-ONLY "v" pins keep all three functions with no tied-def
// copy tax: VALU-time 4.12->2.73ms at CB=8. No spill (WRITE_SIZE flat).
//
// GEOMETRY (r9): CB=8 gave only 512 blocks = 2 blocks/CU = 2 waves/SIMD;
// the per-round barrier+LDS exchange couldn't be hidden (stall 2.07ms,
// VALUBusy 57%). CB=4 restores 1024 blocks = 4 independent barrier
// streams/CU (~4 waves/SIMD; r3 measured stall 1.1ms in this geometry).
// launch_bounds(256,4) caps VGPR at 128 so 4 waves/SIMD fit.
#define PIN4(A, U)                                                      \
    asm volatile("" :: "v"(A[U][0]), "v"(A[U][1]), "v"(A[U][2]),        \
                       "v"(A[U][3]))

#define PINALL()                                                        \
  { PIN4(T, 0); PIN4(T, 1); PIN4(T, 2); PIN4(T, 3);                     \
    PIN4(T, 4); PIN4(T, 5); PIN4(T, 6); PIN4(T, 7);                     \
    PIN4(B, 0); PIN4(B, 1); PIN4(B, 2); PIN4(B, 3);                     \
    PIN4(B, 4); PIN4(B, 5); PIN4(B, 6); PIN4(B, 7); }

// In-place rotation of table U at phase P (both na and nb stay renamed).
// Explicit fmaf: guarantees v_mul + v_fma (2 instrs) per row update.
#define UPD(U, P, CC, SS)                                                     \
  { const float c_ = (CC), s_ = (SS);                                         \
    _Pragma("unroll") for (int c = 0; c < CB; ++c) {                          \
      float a = T[((U) + (P)) & 7][c], b = B[((U) - (P) + 8) & 7][c];         \
      T[((U) + (P)) & 7][c] = fmaf(c_, a, -(s_ * b));                         \
      B[((U) - (P) + 8) & 7][c] = fmaf(s_, a, c_ * b); } }

// One round at compile-time phase P. BUF = this round's cs (float4[4]);
// DO_PF: prefetch round RND+2 into BUF (same parity) after last use.
#define PHASE(P, RND, BUF, DO_PF)                                             \
  {                                                                           \
    PINALL();                                                                 \
    float na0[CB], nb0[CB], nbL[CB];                                          \
    { /* u=0: na exported left, nb deferred (tid==0 turnaround) */            \
      const float c_ = BUF[0].x, s_ = BUF[0].y;                               \
      _Pragma("unroll") for (int c = 0; c < CB; ++c) {                        \
        float a = T[(P) & 7][c], b = B[(0 - (P) + 8) & 7][c];                 \
        na0[c] = fmaf(c_, a, -(s_ * b));                                      \
        nb0[c] = fmaf(s_, a, c_ * b); } }                                     \
    float t7[CB];                                                             \
    _Pragma("unroll") for (int c = 0; c < CB; ++c)                            \
      t7[c] = __shfl_down(na0[c], 1);    /* issued early: latency hidden */   \
    UPD(1, P, BUF[0].z, BUF[0].w)                                             \
    UPD(2, P, BUF[1].x, BUF[1].y)                                             \
    UPD(3, P, BUF[1].z, BUF[1].w)                                             \
    UPD(4, P, BUF[2].x, BUF[2].y)                                             \
    UPD(5, P, BUF[2].z, BUF[2].w)                                             \
    UPD(6, P, BUF[3].x, BUF[3].y)                                             \
    { /* u=7: na in place, nb exported right */                               \
      const float c_ = BUF[3].z, s_ = BUF[3].w;                               \
      _Pragma("unroll") for (int c = 0; c < CB; ++c) {                        \
        float a = T[(7 + (P)) & 7][c], b = B[(7 - (P) + 8) & 7][c];           \
        T[(7 + (P)) & 7][c] = fmaf(c_, a, -(s_ * b));                         \
        nbL[c] = fmaf(s_, a, c_ * b); } }                                     \
    if (DO_PF) { /* after last BUF read: WAR keeps it here; used at P+2 */    \
      const float4* pf_ = csp + (size_t)((RND) + 2) * (NPAIRS / 2);           \
      BUF[0] = pf_[0]; BUF[1] = pf_[1]; BUF[2] = pf_[2]; BUF[3] = pf_[3];     \
    }                                                                         \
    float bi[CB];                                                             \
    _Pragma("unroll") for (int c = 0; c < CB; ++c)                            \
      bi[c] = __shfl_up(nbL[c], 1);                                           \
    if (lane == 0) { _Pragma("unroll") for (int c = 0; c < CB; ++c)           \
        naBuf[(P) & 1][wave][c] = na0[c]; }                                   \
    if (lane == 63) { _Pragma("unroll") for (int c = 0; c < CB; ++c)          \
        nbBuf[(P) & 1][wave][c] = nbL[c]; }                                   \
    __syncthreads();                                                          \
    if (lane == 63) {                                                         \
      if (wave < NWAVES - 1) { _Pragma("unroll")                              \
        for (int c = 0; c < CB; ++c) t7[c] = naBuf[(P) & 1][wave + 1][c]; }   \
      else { _Pragma("unroll")                                                \
        for (int c = 0; c < CB; ++c) t7[c] = nbL[c]; } }                      \
    if (lane == 0 && wave > 0) { _Pragma("unroll")                            \
      for (int c = 0; c < CB; ++c) bi[c] = nbBuf[(P) & 1][wave - 1][c]; }     \
    _Pragma("unroll") for (int c = 0; c < CB; ++c) {                          \
      T[(P) & 7][c] = t7[c];                       /* top import slot */      \
      B[(0 - (P) + 8) & 7][c] = (tid == 0) ? na0[c] : nb0[c];                 \
      B[(7 - (P) + 8) & 7][c] = (tid == 0) ? nb0[c] : bi[c];                  \
    }                                                                         \
  }

__global__ __launch_bounds__(NTHREADS, 4)
void rotmat_systolic(const float2* __restrict__ cs,
                     float* __restrict__ out) {
    __shared__ float naBuf[2][NWAVES][CB];
    __shared__ float nbBuf[2][NWAVES][CB];

    const int tid  = threadIdx.x;
    const int lane = tid & 63;
    const int wave = tid >> 6;
    const int col0 = blockIdx.x * CB;

    float T[TPT][CB], B[TPT][CB];
    // phase 0: logical top[u] -> T[u] (row g), bot[u] -> B[u] (row 4095-g)
#pragma unroll
    for (int u = 0; u < TPT; ++u) {
        int g = tid * TPT + u;
        int rowB = NR - g;            // g=0 -> 4095 (fixed player) too
#pragma unroll
        for (int c = 0; c < CB; ++c) {
            T[u][c] = (g == col0 + c) ? 1.f : 0.f;
            B[u][c] = (rowB == col0 + c) ? 1.f : 0.f;
        }
    }

    // cs as float4: round r, thread quads at csp + r*1024 + {0,1,2,3}
    const float4* csp = (const float4*)cs + (size_t)tid * (TPT / 2);
    float4 csbE[4], csbO[4];
    { const float4* p = csp;                                   // round 0
      csbE[0] = p[0]; csbE[1] = p[1]; csbE[2] = p[2]; csbE[3] = p[3]; }
    { const float4* p = csp + (size_t)1 * (NPAIRS / 2);        // round 1
      csbO[0] = p[0]; csbO[1] = p[1]; csbO[2] = p[2]; csbO[3] = p[3]; }

    int r = 0;
    for (int it = 0; it < 511; ++it, r += 8) {   // rounds 0..4087
        PHASE(0, r,     csbE, 1)
        PHASE(1, r + 1, csbO, 1)
        PHASE(2, r + 2, csbE, 1)
        PHASE(3, r + 3, csbO, 1)
        PHASE(4, r + 4, csbE, 1)
        PHASE(5, r + 5, csbO, 1)
        PHASE(6, r + 6, csbE, 1)
        PHASE(7, r + 7, csbO, 1)
    }
    // tail: rounds 4088..4094 (phases 0..6); last valid prefetch is 4094
    PHASE(0, r,     csbE, 1)
    PHASE(1, r + 1, csbO, 1)
    PHASE(2, r + 2, csbE, 1)
    PHASE(3, r + 3, csbO, 1)
    PHASE(4, r + 4, csbE, 1)
    PHASE(5, r + 5, csbO, 0)
    PHASE(6, r + 6, csbE, 0)

    // final phase index Q = NR mod 8 = 7:
    // logical top[u] -> T[(u+7)&7], bot[u] -> B[(u-7)&7] = B[(u+1)&7]
#pragma unroll
    for (int u = 0; u < TPT; ++u) {
        int g = tid * TPT + u;
        int rowB = NR - g;
        float* Tp = T[(u + 7) & 7];
        float* Bp = B[(u + 1) & 7];
        *(float4*)&out[(size_t)g * NDIM + col0] =
            make_float4(Tp[0], Tp[1], Tp[2], Tp[3]);
        *(float4*)&out[(size_t)rowB * NDIM + col0] =
            make_float4(Bp[0], Bp[1], Bp[2], Bp[3]);
    }
}

extern "C" void kernel_launch(void* const* d_in, const int* in_sizes, int n_in,
                              void* d_out, int out_size, void* d_ws, size_t ws_size,
                              hipStream_t stream) {
    const float* thetas      = (const float*)d_in[0];
    const int*   round_theta = (const int*)d_in[3];
    float*       out         = (float*)d_out;

    const int total = NR * NPAIRS;
    float2* cs = (float2*)d_ws;   // 67 MB workspace (verified sufficient)

    cs_precompute<<<(total + 255) / 256, 256, 0, stream>>>(
        thetas, round_theta, cs, total);
    rotmat_systolic<<<NDIM / CB, NTHREADS, 0, stream>>>(cs, out);
}

// Round 10
// 4104.326 us; speedup vs baseline: 7.1815x; 7.1815x over previous
//
#include <hip/hip_runtime.h>
#include <math.h>

#define NDIM 4096
#define NR   4095        // rounds = N-1 (rotating positions)
#define NPAIRS 2048      // N/2 tables
#define CB   8           // columns per workgroup slice
#define NTHREADS 256
#define NWAVES (NTHREADS / 64)   // 4
#define TPT  8           // tables per thread (NPAIRS / NTHREADS)

// Precompute (c, s) per (round, table); bake in the orientation sign:
// table k at round r holds players a=(r+k)%NR (top) and b=(r-k)%NR (bottom,
// or 4095 fixed for k=0). Reference rotates (i,j)=(min,max) with
// U[i]=c*Ui-s*Uj, U[j]=s*Ui+c*Uj. If top==j negate s. top>bottom iff 0<k<=r<NR-k.
__global__ void cs_precompute(const float* __restrict__ thetas,
                              const int* __restrict__ round_theta,
                              float2* __restrict__ cs, int total) {
    int idx = blockIdx.x * blockDim.x + threadIdx.x;
    if (idx >= total) return;
    int r = idx / NPAIRS;
    int k = idx - r * NPAIRS;
    float th = thetas[round_theta[idx]];
    float s, c;
    sincosf(th, &s, &c);
    if (k > 0 && k <= r && r < NR - k) s = -s;
    cs[idx] = make_float2(c, s);
}

// Register-systolic circle method, phase-rotated in-place update, TPT=8.
// At phase p (= round mod 8): logical top[u] lives in T[(u+p)&7],
// logical bot[u] in B[(u-p)&7]. The per-round ring shift (top[u-1]<-na[u],
// bot[u+1]<-nb[u]) is a pure RENAME for u=1..6; boundary traffic (na of
// first table, nb of last) via shfl +/-1 lane and a tiny LDS ping-pong.
//
// PIN HISTORY (hard-won; the pins serve THREE functions):
//   (1) keep T/B scalarized in SSA (r7: NO pins -> SROA gave up, arrays
//       went to SCRATCH: 136GB spill traffic, 31ms. Pins are mandatory.)
//   (2) keep T/B out of AGPRs
//   (3) asm volatile = schedule fence containing prefetch hoist (r4)
// r8 proved INPUT-ONLY "v" pins keep all three with no tied-def copy tax.
// REGISTER RULE (r9 disaster): never cap the file below live-set +
// prefetch headroom. (256,4) forced a 128 cap -> T/B to scratch, 86GB
// writes, 29.8ms. Keep (256,2); occupancy comes from natural allocation.
//
// BARRIER (r10): __syncthreads() emits s_waitcnt vmcnt(0) lgkmcnt(0)
// before s_barrier -> drains the cs prefetch (needed only at r+2) at
// EVERY round. Swap to raw s_barrier + lgkmcnt(0): LDS exchange stays
// correct (writes visible before barrier), global loads stay in flight
// across rounds; compiler's own vmcnt wait before BUF use keeps dataflow.
#define XBAR()                                                          \
  { asm volatile("s_waitcnt lgkmcnt(0)" ::: "memory");                  \
    __builtin_amdgcn_s_barrier(); }

#define PIN8(A, U)                                                      \
    asm volatile("" :: "v"(A[U][0]), "v"(A[U][1]), "v"(A[U][2]),        \
                       "v"(A[U][3]), "v"(A[U][4]), "v"(A[U][5]),        \
                       "v"(A[U][6]), "v"(A[U][7]))

#define PINALL()                                                        \
  { PIN8(T, 0); PIN8(T, 1); PIN8(T, 2); PIN8(T, 3);                     \
    PIN8(T, 4); PIN8(T, 5); PIN8(T, 6); PIN8(T, 7);                     \
    PIN8(B, 0); PIN8(B, 1); PIN8(B, 2); PIN8(B, 3);                     \
    PIN8(B, 4); PIN8(B, 5); PIN8(B, 6); PIN8(B, 7); }

// In-place rotation of table U at phase P (both na and nb stay renamed).
// Explicit fmaf: guarantees v_mul + v_fma (2 instrs) per row update.
#define UPD(U, P, CC, SS)                                                     \
  { const float c_ = (CC), s_ = (SS);                                         \
    _Pragma("unroll") for (int c = 0; c < CB; ++c) {                          \
      float a = T[((U) + (P)) & 7][c], b = B[((U) - (P) + 8) & 7][c];         \
      T[((U) + (P)) & 7][c] = fmaf(c_, a, -(s_ * b));                         \
      B[((U) - (P) + 8) & 7][c] = fmaf(s_, a, c_ * b); } }

// One round at compile-time phase P. BUF = this round's cs (float4[4]);
// DO_PF: prefetch round RND+2 into BUF (same parity) after last use.
#define PHASE(P, RND, BUF, DO_PF)                                             \
  {                                                                           \
    PINALL();                                                                 \
    float na0[CB], nb0[CB], nbL[CB];                                          \
    { /* u=0: na exported left, nb deferred (tid==0 turnaround) */            \
      const float c_ = BUF[0].x, s_ = BUF[0].y;                               \
      _Pragma("unroll") for (int c = 0; c < CB; ++c) {                        \
        float a = T[(P) & 7][c], b = B[(0 - (P) + 8) & 7][c];                 \
        na0[c] = fmaf(c_, a, -(s_ * b));                                      \
        nb0[c] = fmaf(s_, a, c_ * b); } }                                     \
    float t7[CB];                                                             \
    _Pragma("unroll") for (int c = 0; c < CB; ++c)                            \
      t7[c] = __shfl_down(na0[c], 1);    /* issued early: latency hidden */   \
    UPD(1, P, BUF[0].z, BUF[0].w)                                             \
    UPD(2, P, BUF[1].x, BUF[1].y)                                             \
    UPD(3, P, BUF[1].z, BUF[1].w)                                             \
    UPD(4, P, BUF[2].x, BUF[2].y)                                             \
    UPD(5, P, BUF[2].z, BUF[2].w)                                             \
    UPD(6, P, BUF[3].x, BUF[3].y)                                             \
    { /* u=7: na in place, nb exported right */                               \
      const float c_ = BUF[3].z, s_ = BUF[3].w;                               \
      _Pragma("unroll") for (int c = 0; c < CB; ++c) {                        \
        float a = T[(7 + (P)) & 7][c], b = B[(7 - (P) + 8) & 7][c];           \
        T[(7 + (P)) & 7][c] = fmaf(c_, a, -(s_ * b));                         \
        nbL[c] = fmaf(s_, a, c_ * b); } }                                     \
    if (DO_PF) { /* after last BUF read: WAR keeps it here; used at P+2 */    \
      const float4* pf_ = csp + (size_t)((RND) + 2) * (NPAIRS / 2);           \
      BUF[0] = pf_[0]; BUF[1] = pf_[1]; BUF[2] = pf_[2]; BUF[3] = pf_[3];     \
    }                                                                         \
    float bi[CB];                                                             \
    _Pragma("unroll") for (int c = 0; c < CB; ++c)                            \
      bi[c] = __shfl_up(nbL[c], 1);                                           \
    if (lane == 0) { _Pragma("unroll") for (int c = 0; c < CB; ++c)           \
        naBuf[(P) & 1][wave][c] = na0[c]; }                                   \
    if (lane == 63) { _Pragma("unroll") for (int c = 0; c < CB; ++c)          \
        nbBuf[(P) & 1][wave][c] = nbL[c]; }                                   \
    XBAR();                                                                   \
    if (lane == 63) {                                                         \
      if (wave < NWAVES - 1) { _Pragma("unroll")                              \
        for (int c = 0; c < CB; ++c) t7[c] = naBuf[(P) & 1][wave + 1][c]; }   \
      else { _Pragma("unroll")                                                \
        for (int c = 0; c < CB; ++c) t7[c] = nbL[c]; } }                      \
    if (lane == 0 && wave > 0) { _Pragma("unroll")                            \
      for (int c = 0; c < CB; ++c) bi[c] = nbBuf[(P) & 1][wave - 1][c]; }     \
    _Pragma("unroll") for (int c = 0; c < CB; ++c) {                          \
      T[(P) & 7][c] = t7[c];                       /* top import slot */      \
      B[(0 - (P) + 8) & 7][c] = (tid == 0) ? na0[c] : nb0[c];                 \
      B[(7 - (P) + 8) & 7][c] = (tid == 0) ? nb0[c] : bi[c];                  \
    }                                                                         \
  }

__global__ __launch_bounds__(NTHREADS, 2)
void rotmat_systolic(const float2* __restrict__ cs,
                     float* __restrict__ out) {
    __shared__ float naBuf[2][NWAVES][CB];
    __shared__ float nbBuf[2][NWAVES][CB];

    const int tid  = threadIdx.x;
    const int lane = tid & 63;
    const int wave = tid >> 6;
    const int col0 = blockIdx.x * CB;

    float T[TPT][CB], B[TPT][CB];
    // phase 0: logical top[u] -> T[u] (row g), bot[u] -> B[u] (row 4095-g)
#pragma unroll
    for (int u = 0; u < TPT; ++u) {
        int g = tid * TPT + u;
        int rowB = NR - g;            // g=0 -> 4095 (fixed player) too
#pragma unroll
        for (int c = 0; c < CB; ++c) {
            T[u][c] = (g == col0 + c) ? 1.f : 0.f;
            B[u][c] = (rowB == col0 + c) ? 1.f : 0.f;
        }
    }

    // cs as float4: round r, thread quads at csp + r*1024 + {0,1,2,3}
    const float4* csp = (const float4*)cs + (size_t)tid * (TPT / 2);
    float4 csbE[4], csbO[4];
    { const float4* p = csp;                                   // round 0
      csbE[0] = p[0]; csbE[1] = p[1]; csbE[2] = p[2]; csbE[3] = p[3]; }
    { const float4* p = csp + (size_t)1 * (NPAIRS / 2);        // round 1
      csbO[0] = p[0]; csbO[1] = p[1]; csbO[2] = p[2]; csbO[3] = p[3]; }

    int r = 0;
    for (int it = 0; it < 511; ++it, r += 8) {   // rounds 0..4087
        PHASE(0, r,     csbE, 1)
        PHASE(1, r + 1, csbO, 1)
        PHASE(2, r + 2, csbE, 1)
        PHASE(3, r + 3, csbO, 1)
        PHASE(4, r + 4, csbE, 1)
        PHASE(5, r + 5, csbO, 1)
        PHASE(6, r + 6, csbE, 1)
        PHASE(7, r + 7, csbO, 1)
    }
    // tail: rounds 4088..4094 (phases 0..6); last valid prefetch is 4094
    PHASE(0, r,     csbE, 1)
    PHASE(1, r + 1, csbO, 1)
    PHASE(2, r + 2, csbE, 1)
    PHASE(3, r + 3, csbO, 1)
    PHASE(4, r + 4, csbE, 1)
    PHASE(5, r + 5, csbO, 0)
    PHASE(6, r + 6, csbE, 0)

    // final phase index Q = NR mod 8 = 7:
    // logical top[u] -> T[(u+7)&7], bot[u] -> B[(u-7)&7] = B[(u+1)&7]
#pragma unroll
    for (int u = 0; u < TPT; ++u) {
        int g = tid * TPT + u;
        int rowB = NR - g;
        float* Tp = T[(u + 7) & 7];
        float* Bp = B[(u + 1) & 7];
        float4* oT = (float4*)&out[(size_t)g * NDIM + col0];
        oT[0] = make_float4(Tp[0], Tp[1], Tp[2], Tp[3]);
        oT[1] = make_float4(Tp[4], Tp[5], Tp[6], Tp[7]);
        float4* oB = (float4*)&out[(size_t)rowB * NDIM + col0];
        oB[0] = make_float4(Bp[0], Bp[1], Bp[2], Bp[3]);
        oB[1] = make_float4(Bp[4], Bp[5], Bp[6], Bp[7]);
    }
}

extern "C" void kernel_launch(void* const* d_in, const int* in_sizes, int n_in,
                              void* d_out, int out_size, void* d_ws, size_t ws_size,
                              hipStream_t stream) {
    const float* thetas      = (const float*)d_in[0];
    const int*   round_theta = (const int*)d_in[3];
    float*       out         = (float*)d_out;

    const int total = NR * NPAIRS;
    float2* cs = (float2*)d_ws;   // 67 MB workspace (verified sufficient)

    cs_precompute<<<(total + 255) / 256, 256, 0, stream>>>(
        thetas, round_theta, cs, total);
    rotmat_systolic<<<NDIM / CB, NTHREADS, 0, stream>>>(cs, out);
}